// Round 14
// baseline (382.337 us; speedup 1.0000x reference)
//
#include <hip/hip_runtime.h>
#include <math.h>

#define BB 128
#define SS 128
#define AE 65
#define VE 65
#define TE 129
#define PFD 128
#define FUSED 545025UL
#define FUSEDI 545025
#define VSTRIDE 136            // padded w-stride (multiple of 8)
#define APLANE 8840            // 65*136
#define FPP 574976UL           // padded per-b f16 k-extent = 512*1123
#define FPPI 574976
#define KSP 512
#define NBLK 1123              // FPPI / KSP

typedef _Float16 half8 __attribute__((ext_vector_type(8)));
typedef float f32x16 __attribute__((ext_vector_type(16)));

__device__ __forceinline__ void gll16(const void* g, void* l) {
  __builtin_amdgcn_global_load_lds((const __attribute__((address_space(1))) void*)g,
                                   (__attribute__((address_space(3))) void*)l, 16, 0, 0);
}

// ---------------- zero-init accumulators ----------------
__global__ __launch_bounds__(256) void k_zero(float* __restrict__ p, int n) {
  int i = blockIdx.x * 256 + threadIdx.x;
  if (i < n) p[i] = 0.f;
}

// zero the pad holes of Fh: per (b,a,v) w=129..135, plus per-b tail [574600,574976)
__global__ __launch_bounds__(256) void k_fpad(_Float16* __restrict__ Fh) {
  const int b = blockIdx.x;
  _Float16* base = Fh + (size_t)b * FPP;
  for (int i = threadIdx.x; i < 29575; i += 256) {   // 65*65*7
    const int a = i / 455, r = i - a * 455;
    const int v = r / 7, e = r - v * 7;
    base[a * APLANE + v * VSTRIDE + 129 + e] = (_Float16)0.f;
  }
  for (int i = threadIdx.x; i < 376; i += 256) base[574600 + i] = (_Float16)0.f;
}

// ---------------- core v3: MFMA, hi/lo-split operands (f32-exact fusion) ----------
__global__ __launch_bounds__(256) void k_core(
    const float* __restrict__ audio, const float* __restrict__ vision,
    const float* __restrict__ text, _Float16* __restrict__ Fh,
    float* __restrict__ normsq)
{
  const int b  = blockIdx.x;
  const int gy = blockIdx.y;          // a = 1+8gy .. 8+8gy
  const int gz = blockIdx.z;          // w = 64gz .. 64gz+63
  const int tid = threadIdx.x;
  const int wv = tid >> 6, ln = tid & 63;
  const int lr = ln & 31, hb = ln >> 5;

  __shared__ float    sVt[64][132];   // [v-1][s]
  __shared__ float    sAc[8][132];    // [j][s]
  __shared__ _Float16 sTh[64][136];   // [w-local][s]
  __shared__ _Float16 sTl[64][136];   // prescaled *2048

  {
    const float* vb = vision + (size_t)b * SS * 64;
#pragma unroll
    for (int r = 0; r < 32; ++r) {
      const int e = tid + 256 * r;
      sVt[e & 63][e >> 6] = vb[e];
    }
    const float* ab = audio + (size_t)b * SS * 64 + 8 * gy;
#pragma unroll
    for (int r = 0; r < 4; ++r) {
      const int e = tid + 256 * r;
      sAc[e & 7][e >> 3] = ab[(e >> 3) * 64 + (e & 7)];
    }
    const int wbase = 64 * gz;
    const float* tb = text + (size_t)b * SS * 128;
#pragma unroll
    for (int r = 0; r < 32; ++r) {
      const int e = tid + 256 * r;
      const int s = e >> 6, wl = e & 63;
      const int w = wbase + wl;
      const float val = (w == 0) ? 1.f : tb[s * 128 + w - 1];
      const _Float16 th = (_Float16)val;
      sTh[wl][s] = th;
      sTl[wl][s] = (_Float16)((val - (float)th) * 2048.f);
    }
  }
  __syncthreads();

  float ss = 0.f;
  for (int i = 0; i < 8; ++i) {
    const int u  = 8 * wv + i;
    const int rt = u >> 1, wt = u & 1;
    const int j  = rt >> 1, vh = rt & 1;
    const int v0m = 32 * vh;
    const int wl0 = 32 * wt;

    f32x16 acc = {}, accl = {};
#pragma unroll
    for (int ks = 0; ks < 8; ++ks) {
      const int s0 = 16 * ks + 8 * hb;
      const float4 x0 = *(const float4*)&sVt[v0m + lr][s0];
      const float4 x1 = *(const float4*)&sVt[v0m + lr][s0 + 4];
      const float4 a0 = *(const float4*)&sAc[j][s0];
      const float4 a1 = *(const float4*)&sAc[j][s0 + 4];
      const float pp[8] = {a0.x * x0.x, a0.y * x0.y, a0.z * x0.z, a0.w * x0.w,
                           a1.x * x1.x, a1.y * x1.y, a1.z * x1.z, a1.w * x1.w};
      half8 afh, afl;
#pragma unroll
      for (int e = 0; e < 8; ++e) {
        const _Float16 h = (_Float16)pp[e];
        afh[e] = h;
        afl[e] = (_Float16)((pp[e] - (float)h) * 2048.f);
      }
      const half8 bqh = *(const half8*)&sTh[wl0 + lr][s0];
      const half8 bql = *(const half8*)&sTl[wl0 + lr][s0];
      acc  = __builtin_amdgcn_mfma_f32_32x32x16_f16(afh, bqh, acc,  0, 0, 0);
      accl = __builtin_amdgcn_mfma_f32_32x32x16_f16(afl, bqh, accl, 0, 0, 0);
      accl = __builtin_amdgcn_mfma_f32_32x32x16_f16(afh, bql, accl, 0, 0, 0);
    }

    const int a = 1 + 8 * gy + j;
    _Float16* Fb = Fh + (size_t)b * FPP + (size_t)a * APLANE;
    const int wg = 64 * gz + wl0 + lr;
#pragma unroll
    for (int reg = 0; reg < 16; ++reg) {
      const int crow = (reg & 3) + 8 * (reg >> 2) + 4 * hb;
      const int v = 1 + 32 * vh + crow;
      const float f = acc[reg] + accl[reg] * (1.f / 2048.f);
      ss += f * f;
      Fb[(size_t)v * VSTRIDE + wg] = (_Float16)f;
    }
  }

#pragma unroll
  for (int off = 32; off > 0; off >>= 1) ss += __shfl_down(ss, off);
  if (ln == 0) atomicAdd(&normsq[b], ss);
}

// ---------------- plane a=0: v 0..64, w 0..128 ----------------
__global__ __launch_bounds__(256) void k_pa(
    const float* __restrict__ vision, const float* __restrict__ text,
    _Float16* __restrict__ Fh, float* __restrict__ normsq)
{
  const int b = blockIdx.x;
  const int tid = threadIdx.x;
  const int tw = tid & 15, tv = tid >> 4;
  __shared__ float sv[32][80];
  __shared__ float st[32][144];
  float acc[5][9];
#pragma unroll
  for (int i = 0; i < 5; ++i)
#pragma unroll
    for (int j = 0; j < 9; ++j) acc[i][j] = 0.f;

  for (int c = 0; c < 4; ++c) {
    const int s0 = 32 * c;
    __syncthreads();
    const float* vbase = &vision[((size_t)(b * SS + s0)) * 64];
#pragma unroll
    for (int r = 0; r < 8; ++r) {
      const int e = tid + 256 * r;
      sv[e >> 6][(e & 63) + 1] = vbase[e];
    }
    const float* tbase = &text[((size_t)(b * SS + s0)) * 128];
#pragma unroll
    for (int r = 0; r < 16; ++r) {
      const int e = tid + 256 * r;
      st[e >> 7][(e & 127) + 1] = tbase[e];
    }
    if (tid < 32) { sv[tid][0] = 1.f; st[tid][0] = 1.f; }
    __syncthreads();
    for (int s = 0; s < 32; ++s) {
      float vr[5], tr[9];
#pragma unroll
      for (int i = 0; i < 5; ++i) {
        const int vx = tv + 16 * i;
        vr[i] = (vx < VE) ? sv[s][vx] : 0.f;
      }
#pragma unroll
      for (int j = 0; j < 9; ++j) {
        const int wx = tw + 16 * j;
        tr[j] = (wx < TE) ? st[s][wx] : 0.f;
      }
#pragma unroll
      for (int i = 0; i < 5; ++i)
#pragma unroll
        for (int j = 0; j < 9; ++j) acc[i][j] += vr[i] * tr[j];
    }
  }
  _Float16* Fb = Fh + (size_t)b * FPP;   // a = 0
  float ss = 0.f;
#pragma unroll
  for (int i = 0; i < 5; ++i) {
    const int v = tv + 16 * i;
    if (v < VE) {
#pragma unroll
      for (int j = 0; j < 9; ++j) {
        const int w = tw + 16 * j;
        if (w < TE) {
          const float m = acc[i][j];
          Fb[(size_t)v * VSTRIDE + w] = (_Float16)m;
          ss += m * m;
        }
      }
    }
  }
#pragma unroll
  for (int off = 32; off > 0; off >>= 1) ss += __shfl_down(ss, off);
  if ((tid & 63) == 0) atomicAdd(&normsq[b], ss);
}

// ---------------- plane v=0: a 1..64, w 0..128 ----------------
__global__ __launch_bounds__(256) void k_pv(
    const float* __restrict__ audio, const float* __restrict__ text,
    _Float16* __restrict__ Fh, float* __restrict__ normsq)
{
  const int b = blockIdx.x;
  const int tid = threadIdx.x;
  const int tw = tid & 15, tv = tid >> 4;
  __shared__ float sa[32][64];
  __shared__ float st[32][144];
  float acc[4][9];
#pragma unroll
  for (int i = 0; i < 4; ++i)
#pragma unroll
    for (int j = 0; j < 9; ++j) acc[i][j] = 0.f;

  for (int c = 0; c < 4; ++c) {
    const int s0 = 32 * c;
    __syncthreads();
    const float* abase = &audio[((size_t)(b * SS + s0)) * 64];
#pragma unroll
    for (int r = 0; r < 8; ++r) {
      const int e = tid + 256 * r;
      sa[e >> 6][e & 63] = abase[e];
    }
    const float* tbase = &text[((size_t)(b * SS + s0)) * 128];
#pragma unroll
    for (int r = 0; r < 16; ++r) {
      const int e = tid + 256 * r;
      st[e >> 7][(e & 127) + 1] = tbase[e];
    }
    if (tid < 32) st[tid][0] = 1.f;
    __syncthreads();
    for (int s = 0; s < 32; ++s) {
      float ar[4], tr[9];
#pragma unroll
      for (int i = 0; i < 4; ++i) ar[i] = sa[s][tv + 16 * i];
#pragma unroll
      for (int j = 0; j < 9; ++j) {
        const int wx = tw + 16 * j;
        tr[j] = (wx < TE) ? st[s][wx] : 0.f;
      }
#pragma unroll
      for (int i = 0; i < 4; ++i)
#pragma unroll
        for (int j = 0; j < 9; ++j) acc[i][j] += ar[i] * tr[j];
    }
  }
  float ss = 0.f;
#pragma unroll
  for (int i = 0; i < 4; ++i) {
    const int a = 1 + tv + 16 * i;
    _Float16* Fb = Fh + (size_t)b * FPP + (size_t)a * APLANE;   // v = 0
#pragma unroll
    for (int j = 0; j < 9; ++j) {
      const int w = tw + 16 * j;
      if (w < TE) {
        const float m = acc[i][j];
        Fb[w] = (_Float16)m;
        ss += m * m;
      }
    }
  }
#pragma unroll
  for (int off = 32; off > 0; off >>= 1) ss += __shfl_down(ss, off);
  if ((tid & 63) == 0) atomicAdd(&normsq[b], ss);
}

// ---------------- column w=128: a 1..64, v 1..64 ----------------
__global__ __launch_bounds__(256) void k_wlast(
    const float* __restrict__ audio, const float* __restrict__ vision,
    const float* __restrict__ text, _Float16* __restrict__ Fh,
    float* __restrict__ Flast, float* __restrict__ normsq)
{
  const int b = blockIdx.x;
  const int tid = threadIdx.x;
  const int tw = tid & 15, tv = tid >> 4;
  __shared__ float sa[32][64];
  __shared__ float sv[32][64];
  __shared__ float swt[32];
  float acc[4][4];
#pragma unroll
  for (int i = 0; i < 4; ++i)
#pragma unroll
    for (int j = 0; j < 4; ++j) acc[i][j] = 0.f;

  for (int c = 0; c < 4; ++c) {
    const int s0 = 32 * c;
    __syncthreads();
    const float* abase = &audio[((size_t)(b * SS + s0)) * 64];
    const float* vbase = &vision[((size_t)(b * SS + s0)) * 64];
#pragma unroll
    for (int r = 0; r < 8; ++r) {
      const int e = tid + 256 * r;
      sa[e >> 6][e & 63] = abase[e];
      sv[e >> 6][e & 63] = vbase[e];
    }
    if (tid < 32) swt[tid] = text[((size_t)(b * SS + s0 + tid)) * 128 + 127];
    __syncthreads();
    for (int s = 0; s < 32; ++s) {
      const float t = swt[s];
      float ar[4], vr[4];
#pragma unroll
      for (int i = 0; i < 4; ++i) ar[i] = sa[s][tv + 16 * i] * t;
#pragma unroll
      for (int j = 0; j < 4; ++j) vr[j] = sv[s][tw + 16 * j];
#pragma unroll
      for (int i = 0; i < 4; ++i)
#pragma unroll
        for (int j = 0; j < 4; ++j) acc[i][j] += ar[i] * vr[j];
    }
  }
  float ss = 0.f;
#pragma unroll
  for (int i = 0; i < 4; ++i) {
    const int a = 1 + tv + 16 * i;
    _Float16* Fb = Fh + (size_t)b * FPP + (size_t)a * APLANE;
#pragma unroll
    for (int j = 0; j < 4; ++j) {
      const int v = 1 + tw + 16 * j;
      float m = acc[i][j];
      ss += m * m;
      if (a == 64 && v == 64) { Flast[b] = m; m = 0.f; }  // exact fp32 path via k_final
      Fb[(size_t)v * VSTRIDE + 128] = (_Float16)m;
    }
  }
#pragma unroll
  for (int off = 32; off > 0; off >>= 1) ss += __shfl_down(ss, off);
  if ((tid & 63) == 0) atomicAdd(&normsq[b], ss);
}

// ---------------- deep-K MFMA GEMM v8: counted-vmcnt pipeline (T4), raw barrier ----
// grid 1123. 4 waves; wave wv owns p-rows [32wv,32wv+32), all 128 b.
// A: per-lane W1 f32 loads for step T+1 issued during T (depth 1, registers).
// B: gll16 into 3 LDS buffers, staged 2 steps ahead (depth 2).
// Top of step T: s_waitcnt vmcnt(2) retires A(T)+B(T) in order, leaves B(T+1)'s
// 2 DMAs in flight ACROSS the raw s_barrier (never drains to 0 mid-loop).
__global__ __launch_bounds__(256) void k_gemm(
    const float* __restrict__ W1, const _Float16* __restrict__ Fh,
    float* __restrict__ parts)
{
  __shared__ _Float16 sB[3][4096];   // 3 x 8 KB

  const int tid = threadIdx.x;
  const int wv = tid >> 6, ln = tid & 63;
  const int lb = ln & 31, hb = ln >> 5;
  const int p  = (wv << 5) + lb;
  const int kp0 = blockIdx.x * KSP;
  const int kpl0 = kp0 + (hb << 3);
  const int kpl1 = kpl0 + 16;

  // padded-k -> W1-k trackers (r8-proven; advance +32/step, rollover +25)
  int w0, ko0, w1, ko1;
  {
    const int a0 = kpl0 / APLANE; const int r0 = kpl0 - a0 * APLANE;
    const int v0 = r0 / VSTRIDE;  w0 = r0 - v0 * VSTRIDE;
    ko0 = a0 * 8385 + v0 * 129 + w0;
    const int a1 = kpl1 / APLANE; const int r1 = kpl1 - a1 * APLANE;
    const int v1 = r1 / VSTRIDE;  w1 = r1 - v1 * VSTRIDE;
    ko1 = a1 * 8385 + v1 * 129 + w1;
  }

  const float* wrow = W1 + (size_t)p * FUSED;

  // B staging pointers (pre-swizzled global src, linear LDS dest)
  const int brow0 = (wv << 5) + (ln >> 2);
  const int slogB = (ln & 3) ^ ((ln >> 2) & 3);
  const _Float16* FhP0 = Fh + (size_t)brow0 * FPP + kp0 + (slogB << 3);
  const _Float16* FhP1 = FhP0 + (size_t)16 * FPP;

  f32x16 acc0 = {}, acc1 = {}, acc2 = {}, acc3 = {};
  float4 xa[4];

  // clamp only fires where Fh==0 (tail pad / the zeroed (64,64,128) group)
#define LOADA                                                              \
  {                                                                        \
    const int kc0 = (ko0 <= 545017) ? ko0 : 545008;                        \
    const int kc1 = (ko1 <= 545017) ? ko1 : 545008;                        \
    __builtin_memcpy(&xa[0], wrow + kc0, 16);                              \
    __builtin_memcpy(&xa[1], wrow + kc0 + 4, 16);                          \
    __builtin_memcpy(&xa[2], wrow + kc1, 16);                              \
    __builtin_memcpy(&xa[3], wrow + kc1 + 4, 16);                          \
    w0 += 32; if (w0 >= VSTRIDE) { w0 -= VSTRIDE; ko0 += 25; } else ko0 += 32; \
    w1 += 32; if (w1 >= VSTRIDE) { w1 -= VSTRIDE; ko1 += 25; } else ko1 += 32; \
  }

#define STAGEB(BUF, KOFF)                                                 \
  {                                                                       \
    gll16(FhP0 + (KOFF), (char*)&sB[BUF][0] + ((wv << 5) << 6));          \
    gll16(FhP1 + (KOFF), (char*)&sB[BUF][0] + (((wv << 5) + 16) << 6));   \
  }

  // one pipeline step; T and WSTR are literals (fully unrolled below)
#define GSTEP(T, WSTR)                                                         \
  {                                                                            \
    asm volatile("s_waitcnt " WSTR ::: "memory");                              \
    __builtin_amdgcn_sched_barrier(0);                                         \
    __builtin_amdgcn_s_barrier();                                              \
    __builtin_amdgcn_sched_barrier(0);                                         \
    half8 af0, af1;                                                            \
    af0[0] = (_Float16)xa[0].x; af0[1] = (_Float16)xa[0].y;                    \
    af0[2] = (_Float16)xa[0].z; af0[3] = (_Float16)xa[0].w;                    \
    af0[4] = (_Float16)xa[1].x; af0[5] = (_Float16)xa[1].y;                    \
    af0[6] = (_Float16)xa[1].z; af0[7] = (_Float16)xa[1].w;                    \
    af1[0] = (_Float16)xa[2].x; af1[1] = (_Float16)xa[2].y;                    \
    af1[2] = (_Float16)xa[2].z; af1[3] = (_Float16)xa[2].w;                    \
    af1[4] = (_Float16)xa[3].x; af1[5] = (_Float16)xa[3].y;                    \
    af1[6] = (_Float16)xa[3].z; af1[7] = (_Float16)xa[3].w;                    \
    if ((T) + 1 < 16) { LOADA }                                                \
    if ((T) + 2 < 16) { STAGEB(((T) + 2) % 3, ((T) + 2) * 32) }                \
    __builtin_amdgcn_sched_barrier(0);                                         \
    {                                                                          \
      const _Float16* sBb = &sB[(T) % 3][0];                                   \
      {                                                                        \
        const int sl = hb;                                                     \
        const char* bbase = (const char*)sBb + (lb << 6) + ((sl ^ (lb & 3)) << 4); \
        const half8 b0 = *(const half8*)(bbase);                               \
        const half8 b1 = *(const half8*)(bbase + 2048);                        \
        const half8 b2 = *(const half8*)(bbase + 4096);                        \
        const half8 b3 = *(const half8*)(bbase + 6144);                        \
        acc0 = __builtin_amdgcn_mfma_f32_32x32x16_f16(af0, b0, acc0, 0, 0, 0); \
        acc1 = __builtin_amdgcn_mfma_f32_32x32x16_f16(af0, b1, acc1, 0, 0, 0); \
        acc2 = __builtin_amdgcn_mfma_f32_32x32x16_f16(af0, b2, acc2, 0, 0, 0); \
        acc3 = __builtin_amdgcn_mfma_f32_32x32x16_f16(af0, b3, acc3, 0, 0, 0); \
      }                                                                        \
      {                                                                        \
        const int sl = 2 + hb;                                                 \
        const char* bbase = (const char*)sBb + (lb << 6) + ((sl ^ (lb & 3)) << 4); \
        const half8 b0 = *(const half8*)(bbase);                               \
        const half8 b1 = *(const half8*)(bbase + 2048);                        \
        const half8 b2 = *(const half8*)(bbase + 4096);                        \
        const half8 b3 = *(const half8*)(bbase + 6144);                        \
        acc0 = __builtin_amdgcn_mfma_f32_32x32x16_f16(af1, b0, acc0, 0, 0, 0); \
        acc1 = __builtin_amdgcn_mfma_f32_32x32x16_f16(af1, b1, acc1, 0, 0, 0); \
        acc2 = __builtin_amdgcn_mfma_f32_32x32x16_f16(af1, b2, acc2, 0, 0, 0); \
        acc3 = __builtin_amdgcn_mfma_f32_32x32x16_f16(af1, b3, acc3, 0, 0, 0); \
      }                                                                        \
    }                                                                          \
  }

  // prologue: A(0), B(0), B(1) in flight (8 outstanding)
  LOADA
  STAGEB(0, 0)
  STAGEB(1, 32)

  GSTEP(0,  "vmcnt(2)")
  GSTEP(1,  "vmcnt(2)")
  GSTEP(2,  "vmcnt(2)")
  GSTEP(3,  "vmcnt(2)")
  GSTEP(4,  "vmcnt(2)")
  GSTEP(5,  "vmcnt(2)")
  GSTEP(6,  "vmcnt(2)")
  GSTEP(7,  "vmcnt(2)")
  GSTEP(8,  "vmcnt(2)")
  GSTEP(9,  "vmcnt(2)")
  GSTEP(10, "vmcnt(2)")
  GSTEP(11, "vmcnt(2)")
  GSTEP(12, "vmcnt(2)")
  GSTEP(13, "vmcnt(2)")
  GSTEP(14, "vmcnt(2)")
  GSTEP(15, "vmcnt(0)")
#undef GSTEP
#undef LOADA
#undef STAGEB

  // coalesced partial store: thread's 64 floats contiguous
  f32x16* o = (f32x16*)(parts + ((size_t)blockIdx.x * 256 + tid) * 64);
  o[0] = acc0; o[1] = acc1; o[2] = acc2; o[3] = acc3;
}

// ---------------- reduce partials -> y1pre[b][p] ----------------
__global__ __launch_bounds__(256) void k_red(const float* __restrict__ parts,
                                             float* __restrict__ y1pre)
{
  const int tid = threadIdx.x;
  const int T = blockIdx.x * 4 + (tid >> 6);
  const int R = tid & 63;
  float s = 0.f;
  for (int sl = blockIdx.y; sl < NBLK; sl += 16)
    s += parts[(size_t)sl * 16384 + T * 64 + R];
  const int wv2 = T >> 6, hb2 = (T >> 5) & 1, lb2 = T & 31;
  const int q = R >> 4, rg = R & 15;
  const int b = q * 32 + lb2;
  const int pp = wv2 * 32 + (rg & 3) + 8 * (rg >> 2) + 4 * hb2;
  atomicAdd(&y1pre[b * PFD + pp], s);
}

// ---------------- finalize: MLP per batch ----------------
__global__ __launch_bounds__(128) void k_final(
    const float* __restrict__ y1pre, const float* __restrict__ b1,
    const float* __restrict__ W2, const float* __restrict__ b2,
    const float* __restrict__ W3, const float* __restrict__ b3,
    const float* __restrict__ W1, const float* __restrict__ Flast,
    float* __restrict__ out)
{
  const int b = blockIdx.x, p = threadIdx.x;
  __shared__ float y1[PFD];
  __shared__ float red[PFD];
  const float extra = W1[(size_t)p * FUSED + (FUSED - 1)] * Flast[b];
  y1[p] = fmaxf(y1pre[(size_t)b * PFD + p] + extra + b1[p], 0.f);
  __syncthreads();
  float s = b2[p];
  for (int k = 0; k < PFD; ++k) s += y1[k] * W2[p * PFD + k];
  const float y2 = fmaxf(s, 0.f);
  red[p] = y2 * W3[p];
  __syncthreads();
  for (int off = 64; off > 0; off >>= 1) {
    if (p < off) red[p] += red[p + off];
    __syncthreads();
  }
  if (p == 0) {
    const float x = red[0] + b3[0];
    out[b] = 6.f / (1.f + expf(-x)) - 3.f;
  }
}

__global__ __launch_bounds__(128) void k_reg(const float* __restrict__ normsq,
                                             float* __restrict__ out)
{
  const int t = threadIdx.x;
  __shared__ float red[BB];
  red[t] = sqrtf(normsq[t]);
  __syncthreads();
  for (int off = 64; off > 0; off >>= 1) {
    if (t < off) red[t] += red[t + off];
    __syncthreads();
  }
  // tmp = sqrt(64*64*128/128) = 64 exactly; mean over B
  if (t == 0) out[BB] = 64.f * red[0] / (float)BB;
}

extern "C" void kernel_launch(void* const* d_in, const int* in_sizes, int n_in,
                              void* d_out, int out_size, void* d_ws, size_t ws_size,
                              hipStream_t stream) {
  const float* audio  = (const float*)d_in[0];
  const float* vision = (const float*)d_in[1];
  const float* text   = (const float*)d_in[2];
  const float* W1     = (const float*)d_in[3];
  const float* b1     = (const float*)d_in[4];
  const float* W2     = (const float*)d_in[5];
  const float* b2     = (const float*)d_in[6];
  const float* W3     = (const float*)d_in[7];
  const float* b3     = (const float*)d_in[8];
  float* out = (float*)d_out;

  // ws layout (proven bound ws >= 279,183,872 B):
  // [y1pre 64KB][normsq][Flast] | Fh @131072 (147,193,856 B) |
  // parts @147,324,928 (1123*64KB = 73,596,928 B) -> total 220,921,856 B
  float* y1pre  = (float*)d_ws;
  float* normsq = y1pre + BB * PFD;
  float* Flast  = normsq + BB;
  _Float16* Fh  = (_Float16*)((char*)d_ws + 131072);
  float* parts  = (float*)((char*)d_ws + 147324928);

  k_zero<<<65, 256, 0, stream>>>(y1pre, BB * PFD + 2 * BB);
  k_fpad<<<BB, 256, 0, stream>>>(Fh);

  k_core<<<dim3(BB, 8, 2), 256, 0, stream>>>(audio, vision, text, Fh, normsq);
  k_pa<<<BB, 256, 0, stream>>>(vision, text, Fh, normsq);
  k_pv<<<BB, 256, 0, stream>>>(audio, text, Fh, normsq);
  k_wlast<<<BB, 256, 0, stream>>>(audio, vision, text, Fh, Flast, normsq);

  k_gemm<<<NBLK, 256, 0, stream>>>(W1, Fh, parts);
  k_red<<<dim3(64, 16), 256, 0, stream>>>(parts, y1pre);

  k_final<<<BB, PFD, 0, stream>>>(y1pre, b1, W2, b2, W3, b3, W1, Flast, out);
  k_reg<<<1, BB, 0, stream>>>(normsq, out);
}

// Round 15
// 335.295 us; speedup vs baseline: 1.1403x; 1.1403x over previous
//
#include <hip/hip_runtime.h>
#include <math.h>

#define BB 128
#define SS 128
#define AE 65
#define VE 65
#define TE 129
#define PFD 128
#define FUSED 545025UL
#define FUSEDI 545025
#define VSTRIDE 136            // padded w-stride (multiple of 8)
#define APLANE 8840            // 65*136
#define FPP 574976UL           // padded per-b f16 k-extent = 512*1123
#define FPPI 574976
#define KSP 512
#define NBLK 1123              // FPPI / KSP

typedef _Float16 half8 __attribute__((ext_vector_type(8)));
typedef float f32x16 __attribute__((ext_vector_type(16)));

__device__ __forceinline__ void gll16(const void* g, void* l) {
  __builtin_amdgcn_global_load_lds((const __attribute__((address_space(1))) void*)g,
                                   (__attribute__((address_space(3))) void*)l, 16, 0, 0);
}

// ---------------- init: zero accumulators + zero Fh pad holes (merged) ----------
__global__ __launch_bounds__(256) void k_initf(_Float16* __restrict__ Fh,
                                               float* __restrict__ y1pre,
                                               float* __restrict__ normsq,
                                               float* __restrict__ Flast) {
  const int b = blockIdx.x;
  const int tid = threadIdx.x;
  _Float16* base = Fh + (size_t)b * FPP;
  for (int i = tid; i < 29575; i += 256) {   // 65*65*7 w-pad holes
    const int a = i / 455, r = i - a * 455;
    const int v = r / 7, e = r - v * 7;
    base[a * APLANE + v * VSTRIDE + 129 + e] = (_Float16)0.f;
  }
  for (int i = tid; i < 376; i += 256) base[574600 + i] = (_Float16)0.f;
  if (tid < PFD) y1pre[b * PFD + tid] = 0.f;
  if (tid == 128) normsq[b] = 0.f;
  if (tid == 129) Flast[b] = 0.f;
}

// ---------------- core v3: MFMA, hi/lo-split operands (f32-exact fusion) ----------
__global__ __launch_bounds__(256) void k_core(
    const float* __restrict__ audio, const float* __restrict__ vision,
    const float* __restrict__ text, _Float16* __restrict__ Fh,
    float* __restrict__ normsq)
{
  const int b  = blockIdx.x;
  const int gy = blockIdx.y;          // a = 1+8gy .. 8+8gy
  const int gz = blockIdx.z;          // w = 64gz .. 64gz+63
  const int tid = threadIdx.x;
  const int wv = tid >> 6, ln = tid & 63;
  const int lr = ln & 31, hb = ln >> 5;

  __shared__ float    sVt[64][132];   // [v-1][s]
  __shared__ float    sAc[8][132];    // [j][s]
  __shared__ _Float16 sTh[64][136];   // [w-local][s]
  __shared__ _Float16 sTl[64][136];   // prescaled *2048

  {
    const float* vb = vision + (size_t)b * SS * 64;
#pragma unroll
    for (int r = 0; r < 32; ++r) {
      const int e = tid + 256 * r;
      sVt[e & 63][e >> 6] = vb[e];
    }
    const float* ab = audio + (size_t)b * SS * 64 + 8 * gy;
#pragma unroll
    for (int r = 0; r < 4; ++r) {
      const int e = tid + 256 * r;
      sAc[e & 7][e >> 3] = ab[(e >> 3) * 64 + (e & 7)];
    }
    const int wbase = 64 * gz;
    const float* tb = text + (size_t)b * SS * 128;
#pragma unroll
    for (int r = 0; r < 32; ++r) {
      const int e = tid + 256 * r;
      const int s = e >> 6, wl = e & 63;
      const int w = wbase + wl;
      const float val = (w == 0) ? 1.f : tb[s * 128 + w - 1];
      const _Float16 th = (_Float16)val;
      sTh[wl][s] = th;
      sTl[wl][s] = (_Float16)((val - (float)th) * 2048.f);
    }
  }
  __syncthreads();

  float ss = 0.f;
  for (int i = 0; i < 8; ++i) {
    const int u  = 8 * wv + i;
    const int rt = u >> 1, wt = u & 1;
    const int j  = rt >> 1, vh = rt & 1;
    const int v0m = 32 * vh;
    const int wl0 = 32 * wt;

    f32x16 acc = {}, accl = {};
#pragma unroll
    for (int ks = 0; ks < 8; ++ks) {
      const int s0 = 16 * ks + 8 * hb;
      const float4 x0 = *(const float4*)&sVt[v0m + lr][s0];
      const float4 x1 = *(const float4*)&sVt[v0m + lr][s0 + 4];
      const float4 a0 = *(const float4*)&sAc[j][s0];
      const float4 a1 = *(const float4*)&sAc[j][s0 + 4];
      const float pp[8] = {a0.x * x0.x, a0.y * x0.y, a0.z * x0.z, a0.w * x0.w,
                           a1.x * x1.x, a1.y * x1.y, a1.z * x1.z, a1.w * x1.w};
      half8 afh, afl;
#pragma unroll
      for (int e = 0; e < 8; ++e) {
        const _Float16 h = (_Float16)pp[e];
        afh[e] = h;
        afl[e] = (_Float16)((pp[e] - (float)h) * 2048.f);
      }
      const half8 bqh = *(const half8*)&sTh[wl0 + lr][s0];
      const half8 bql = *(const half8*)&sTl[wl0 + lr][s0];
      acc  = __builtin_amdgcn_mfma_f32_32x32x16_f16(afh, bqh, acc,  0, 0, 0);
      accl = __builtin_amdgcn_mfma_f32_32x32x16_f16(afl, bqh, accl, 0, 0, 0);
      accl = __builtin_amdgcn_mfma_f32_32x32x16_f16(afh, bql, accl, 0, 0, 0);
    }

    const int a = 1 + 8 * gy + j;
    _Float16* Fb = Fh + (size_t)b * FPP + (size_t)a * APLANE;
    const int wg = 64 * gz + wl0 + lr;
#pragma unroll
    for (int reg = 0; reg < 16; ++reg) {
      const int crow = (reg & 3) + 8 * (reg >> 2) + 4 * hb;
      const int v = 1 + 32 * vh + crow;
      const float f = acc[reg] + accl[reg] * (1.f / 2048.f);
      ss += f * f;
      Fb[(size_t)v * VSTRIDE + wg] = (_Float16)f;
    }
  }

#pragma unroll
  for (int off = 32; off > 0; off >>= 1) ss += __shfl_down(ss, off);
  if (ln == 0) atomicAdd(&normsq[b], ss);
}

// ---------------- merged boundary planes: gy=0 a-plane, gy=1 v-plane, gy=2 w=128 ---
__global__ __launch_bounds__(256) void k_planes(
    const float* __restrict__ audio, const float* __restrict__ vision,
    const float* __restrict__ text, _Float16* __restrict__ Fh,
    float* __restrict__ Flast, float* __restrict__ normsq)
{
  const int b = blockIdx.x;
  const int which = blockIdx.y;
  const int tid = threadIdx.x;
  const int tw = tid & 15, tv = tid >> 4;
  __shared__ __align__(16) char smem[28800];

  float ss = 0.f;

  if (which == 0) {
    // -------- plane a=0: v 0..64, w 0..128 --------
    float (*sv)[80]  = (float(*)[80])smem;
    float (*st)[144] = (float(*)[144])(smem + 10240);
    float acc[5][9];
#pragma unroll
    for (int i = 0; i < 5; ++i)
#pragma unroll
      for (int j = 0; j < 9; ++j) acc[i][j] = 0.f;

    for (int c = 0; c < 4; ++c) {
      const int s0 = 32 * c;
      __syncthreads();
      const float* vbase = &vision[((size_t)(b * SS + s0)) * 64];
#pragma unroll
      for (int r = 0; r < 8; ++r) {
        const int e = tid + 256 * r;
        sv[e >> 6][(e & 63) + 1] = vbase[e];
      }
      const float* tbase = &text[((size_t)(b * SS + s0)) * 128];
#pragma unroll
      for (int r = 0; r < 16; ++r) {
        const int e = tid + 256 * r;
        st[e >> 7][(e & 127) + 1] = tbase[e];
      }
      if (tid < 32) { sv[tid][0] = 1.f; st[tid][0] = 1.f; }
      __syncthreads();
      for (int s = 0; s < 32; ++s) {
        float vr[5], tr[9];
#pragma unroll
        for (int i = 0; i < 5; ++i) {
          const int vx = tv + 16 * i;
          vr[i] = (vx < VE) ? sv[s][vx] : 0.f;
        }
#pragma unroll
        for (int j = 0; j < 9; ++j) {
          const int wx = tw + 16 * j;
          tr[j] = (wx < TE) ? st[s][wx] : 0.f;
        }
#pragma unroll
        for (int i = 0; i < 5; ++i)
#pragma unroll
          for (int j = 0; j < 9; ++j) acc[i][j] += vr[i] * tr[j];
      }
    }
    _Float16* Fb = Fh + (size_t)b * FPP;   // a = 0
#pragma unroll
    for (int i = 0; i < 5; ++i) {
      const int v = tv + 16 * i;
      if (v < VE) {
#pragma unroll
        for (int j = 0; j < 9; ++j) {
          const int w = tw + 16 * j;
          if (w < TE) {
            const float m = acc[i][j];
            Fb[(size_t)v * VSTRIDE + w] = (_Float16)m;
            ss += m * m;
          }
        }
      }
    }
  } else if (which == 1) {
    // -------- plane v=0: a 1..64, w 0..128 --------
    float (*sa)[64]  = (float(*)[64])smem;
    float (*st)[144] = (float(*)[144])(smem + 10240);
    float acc[4][9];
#pragma unroll
    for (int i = 0; i < 4; ++i)
#pragma unroll
      for (int j = 0; j < 9; ++j) acc[i][j] = 0.f;

    for (int c = 0; c < 4; ++c) {
      const int s0 = 32 * c;
      __syncthreads();
      const float* abase = &audio[((size_t)(b * SS + s0)) * 64];
#pragma unroll
      for (int r = 0; r < 8; ++r) {
        const int e = tid + 256 * r;
        sa[e >> 6][e & 63] = abase[e];
      }
      const float* tbase = &text[((size_t)(b * SS + s0)) * 128];
#pragma unroll
      for (int r = 0; r < 16; ++r) {
        const int e = tid + 256 * r;
        st[e >> 7][(e & 127) + 1] = tbase[e];
      }
      if (tid < 32) st[tid][0] = 1.f;
      __syncthreads();
      for (int s = 0; s < 32; ++s) {
        float ar[4], tr[9];
#pragma unroll
        for (int i = 0; i < 4; ++i) ar[i] = sa[s][tv + 16 * i];
#pragma unroll
        for (int j = 0; j < 9; ++j) {
          const int wx = tw + 16 * j;
          tr[j] = (wx < TE) ? st[s][wx] : 0.f;
        }
#pragma unroll
        for (int i = 0; i < 4; ++i)
#pragma unroll
          for (int j = 0; j < 9; ++j) acc[i][j] += ar[i] * tr[j];
      }
    }
#pragma unroll
    for (int i = 0; i < 4; ++i) {
      const int a = 1 + tv + 16 * i;
      _Float16* Fb = Fh + (size_t)b * FPP + (size_t)a * APLANE;   // v = 0
#pragma unroll
      for (int j = 0; j < 9; ++j) {
        const int w = tw + 16 * j;
        if (w < TE) {
          const float m = acc[i][j];
          Fb[w] = (_Float16)m;
          ss += m * m;
        }
      }
    }
  } else {
    // -------- column w=128: a 1..64, v 1..64 --------
    float (*sa)[64] = (float(*)[64])smem;
    float (*sv)[64] = (float(*)[64])(smem + 10240);
    float* swt = (float*)(smem + 10240 + 8192);
    float acc[4][4];
#pragma unroll
    for (int i = 0; i < 4; ++i)
#pragma unroll
      for (int j = 0; j < 4; ++j) acc[i][j] = 0.f;

    for (int c = 0; c < 4; ++c) {
      const int s0 = 32 * c;
      __syncthreads();
      const float* abase = &audio[((size_t)(b * SS + s0)) * 64];
      const float* vbase = &vision[((size_t)(b * SS + s0)) * 64];
#pragma unroll
      for (int r = 0; r < 8; ++r) {
        const int e = tid + 256 * r;
        sa[e >> 6][e & 63] = abase[e];
        sv[e >> 6][e & 63] = vbase[e];
      }
      if (tid < 32) swt[tid] = text[((size_t)(b * SS + s0 + tid)) * 128 + 127];
      __syncthreads();
      for (int s = 0; s < 32; ++s) {
        const float t = swt[s];
        float ar[4], vr[4];
#pragma unroll
        for (int i = 0; i < 4; ++i) ar[i] = sa[s][tv + 16 * i] * t;
#pragma unroll
        for (int j = 0; j < 4; ++j) vr[j] = sv[s][tw + 16 * j];
#pragma unroll
        for (int i = 0; i < 4; ++i)
#pragma unroll
          for (int j = 0; j < 4; ++j) acc[i][j] += ar[i] * vr[j];
      }
    }
#pragma unroll
    for (int i = 0; i < 4; ++i) {
      const int a = 1 + tv + 16 * i;
      _Float16* Fb = Fh + (size_t)b * FPP + (size_t)a * APLANE;
#pragma unroll
      for (int j = 0; j < 4; ++j) {
        const int v = 1 + tw + 16 * j;
        float m = acc[i][j];
        ss += m * m;
        if (a == 64 && v == 64) { Flast[b] = m; m = 0.f; }  // exact fp32 path
        Fb[(size_t)v * VSTRIDE + 128] = (_Float16)m;
      }
    }
  }

#pragma unroll
  for (int off = 32; off > 0; off >>= 1) ss += __shfl_down(ss, off);
  if ((tid & 63) == 0) atomicAdd(&normsq[b], ss);
}

// ---------------- deep-K MFMA GEMM v9: depth-2 A (reg) + depth-2 B (LDS), T4 -------
// grid 1123. 4 waves; wave wv owns p-rows [32wv,32wv+32), all 128 b.
// A: per-lane W1 f32 loads, TWO register sets (P/Q), issued 2 steps ahead.
// B: gll16 into 3 LDS buffers, staged 2 steps ahead.
// Steady queue at top of step T: [A(T):4, B(T):2, A(T+1):4, B(T+1):2] = 12;
// vmcnt(6) retires exactly A(T)+B(T); 6 ops stay in flight across the barrier.
__global__ __launch_bounds__(256) void k_gemm(
    const float* __restrict__ W1, const _Float16* __restrict__ Fh,
    float* __restrict__ parts)
{
  __shared__ _Float16 sB[3][4096];   // 3 x 8 KB

  const int tid = threadIdx.x;
  const int wv = tid >> 6, ln = tid & 63;
  const int lb = ln & 31, hb = ln >> 5;
  const int p  = (wv << 5) + lb;
  const int kp0 = blockIdx.x * KSP;
  const int kpl0 = kp0 + (hb << 3);
  const int kpl1 = kpl0 + 16;

  // padded-k -> W1-k trackers (advance +32/issue, rollover +25)
  int w0, ko0, w1, ko1;
  {
    const int a0 = kpl0 / APLANE; const int r0 = kpl0 - a0 * APLANE;
    const int v0 = r0 / VSTRIDE;  w0 = r0 - v0 * VSTRIDE;
    ko0 = a0 * 8385 + v0 * 129 + w0;
    const int a1 = kpl1 / APLANE; const int r1 = kpl1 - a1 * APLANE;
    const int v1 = r1 / VSTRIDE;  w1 = r1 - v1 * VSTRIDE;
    ko1 = a1 * 8385 + v1 * 129 + w1;
  }

  const float* wrow = W1 + (size_t)p * FUSED;

  // B staging pointers (pre-swizzled global src, linear LDS dest)
  const int brow0 = (wv << 5) + (ln >> 2);
  const int slogB = (ln & 3) ^ ((ln >> 2) & 3);
  const _Float16* FhP0 = Fh + (size_t)brow0 * FPP + kp0 + (slogB << 3);
  const _Float16* FhP1 = FhP0 + (size_t)16 * FPP;

  f32x16 acc0 = {}, acc1 = {}, acc2 = {}, acc3 = {};
  float4 xaP[4], xaQ[4];

  // clamp only fires where Fh==0 (tail pad / the zeroed (64,64,128) group)
#define LOADA(S)                                                           \
  {                                                                        \
    const int kc0 = (ko0 <= 545017) ? ko0 : 545008;                        \
    const int kc1 = (ko1 <= 545017) ? ko1 : 545008;                        \
    __builtin_memcpy(&xa##S[0], wrow + kc0, 16);                           \
    __builtin_memcpy(&xa##S[1], wrow + kc0 + 4, 16);                       \
    __builtin_memcpy(&xa##S[2], wrow + kc1, 16);                           \
    __builtin_memcpy(&xa##S[3], wrow + kc1 + 4, 16);                       \
    w0 += 32; if (w0 >= VSTRIDE) { w0 -= VSTRIDE; ko0 += 25; } else ko0 += 32; \
    w1 += 32; if (w1 >= VSTRIDE) { w1 -= VSTRIDE; ko1 += 25; } else ko1 += 32; \
  }

#define STAGEB(BUF, KOFF)                                                 \
  {                                                                       \
    gll16(FhP0 + (KOFF), (char*)&sB[BUF][0] + ((wv << 5) << 6));          \
    gll16(FhP1 + (KOFF), (char*)&sB[BUF][0] + (((wv << 5) + 16) << 6));   \
  }

#define GSTEP(T, S, WSTR)                                                      \
  {                                                                            \
    asm volatile("s_waitcnt " WSTR ::: "memory");                              \
    __builtin_amdgcn_sched_barrier(0);                                         \
    __builtin_amdgcn_s_barrier();                                              \
    __builtin_amdgcn_sched_barrier(0);                                         \
    half8 af0, af1;                                                            \
    af0[0] = (_Float16)xa##S[0].x; af0[1] = (_Float16)xa##S[0].y;              \
    af0[2] = (_Float16)xa##S[0].z; af0[3] = (_Float16)xa##S[0].w;              \
    af0[4] = (_Float16)xa##S[1].x; af0[5] = (_Float16)xa##S[1].y;              \
    af0[6] = (_Float16)xa##S[1].z; af0[7] = (_Float16)xa##S[1].w;              \
    af1[0] = (_Float16)xa##S[2].x; af1[1] = (_Float16)xa##S[2].y;              \
    af1[2] = (_Float16)xa##S[2].z; af1[3] = (_Float16)xa##S[2].w;              \
    af1[4] = (_Float16)xa##S[3].x; af1[5] = (_Float16)xa##S[3].y;              \
    af1[6] = (_Float16)xa##S[3].z; af1[7] = (_Float16)xa##S[3].w;              \
    if ((T) + 2 < 16) { LOADA(S) STAGEB(((T) + 2) % 3, ((T) + 2) * 32) }       \
    __builtin_amdgcn_sched_barrier(0);                                         \
    {                                                                          \
      const _Float16* sBb = &sB[(T) % 3][0];                                   \
      {                                                                        \
        const int sl = hb;                                                     \
        const char* bbase = (const char*)sBb + (lb << 6) + ((sl ^ (lb & 3)) << 4); \
        const half8 b0 = *(const half8*)(bbase);                               \
        const half8 b1 = *(const half8*)(bbase + 2048);                        \
        const half8 b2 = *(const half8*)(bbase + 4096);                        \
        const half8 b3 = *(const half8*)(bbase + 6144);                        \
        acc0 = __builtin_amdgcn_mfma_f32_32x32x16_f16(af0, b0, acc0, 0, 0, 0); \
        acc1 = __builtin_amdgcn_mfma_f32_32x32x16_f16(af0, b1, acc1, 0, 0, 0); \
        acc2 = __builtin_amdgcn_mfma_f32_32x32x16_f16(af0, b2, acc2, 0, 0, 0); \
        acc3 = __builtin_amdgcn_mfma_f32_32x32x16_f16(af0, b3, acc3, 0, 0, 0); \
      }                                                                        \
      {                                                                        \
        const int sl = 2 + hb;                                                 \
        const char* bbase = (const char*)sBb + (lb << 6) + ((sl ^ (lb & 3)) << 4); \
        const half8 b0 = *(const half8*)(bbase);                               \
        const half8 b1 = *(const half8*)(bbase + 2048);                        \
        const half8 b2 = *(const half8*)(bbase + 4096);                        \
        const half8 b3 = *(const half8*)(bbase + 6144);                        \
        acc0 = __builtin_amdgcn_mfma_f32_32x32x16_f16(af1, b0, acc0, 0, 0, 0); \
        acc1 = __builtin_amdgcn_mfma_f32_32x32x16_f16(af1, b1, acc1, 0, 0, 0); \
        acc2 = __builtin_amdgcn_mfma_f32_32x32x16_f16(af1, b2, acc2, 0, 0, 0); \
        acc3 = __builtin_amdgcn_mfma_f32_32x32x16_f16(af1, b3, acc3, 0, 0, 0); \
      }                                                                        \
    }                                                                          \
  }

  // prologue: A(0), B(0), A(1), B(1) in flight (12 outstanding, oldest = A(0))
  LOADA(P)
  STAGEB(0, 0)
  LOADA(Q)
  STAGEB(1, 32)

  GSTEP(0,  P, "vmcnt(6)")
  GSTEP(1,  Q, "vmcnt(6)")
  GSTEP(2,  P, "vmcnt(6)")
  GSTEP(3,  Q, "vmcnt(6)")
  GSTEP(4,  P, "vmcnt(6)")
  GSTEP(5,  Q, "vmcnt(6)")
  GSTEP(6,  P, "vmcnt(6)")
  GSTEP(7,  Q, "vmcnt(6)")
  GSTEP(8,  P, "vmcnt(6)")
  GSTEP(9,  Q, "vmcnt(6)")
  GSTEP(10, P, "vmcnt(6)")
  GSTEP(11, Q, "vmcnt(6)")
  GSTEP(12, P, "vmcnt(6)")
  GSTEP(13, Q, "vmcnt(6)")
  GSTEP(14, P, "vmcnt(6)")
  GSTEP(15, Q, "vmcnt(0)")
#undef GSTEP
#undef LOADA
#undef STAGEB

  // coalesced partial store: thread's 64 floats contiguous
  f32x16* o = (f32x16*)(parts + ((size_t)blockIdx.x * 256 + tid) * 64);
  o[0] = acc0; o[1] = acc1; o[2] = acc2; o[3] = acc3;
}

// ---------------- reduce partials -> y1pre[b][p] ----------------
__global__ __launch_bounds__(256) void k_red(const float* __restrict__ parts,
                                             float* __restrict__ y1pre)
{
  const int tid = threadIdx.x;
  const int T = blockIdx.x * 4 + (tid >> 6);
  const int R = tid & 63;
  float s = 0.f;
  for (int sl = blockIdx.y; sl < NBLK; sl += 16)
    s += parts[(size_t)sl * 16384 + T * 64 + R];
  const int wv2 = T >> 6, hb2 = (T >> 5) & 1, lb2 = T & 31;
  const int q = R >> 4, rg = R & 15;
  const int b = q * 32 + lb2;
  const int pp = wv2 * 32 + (rg & 3) + 8 * (rg >> 2) + 4 * hb2;
  atomicAdd(&y1pre[b * PFD + pp], s);
}

// ---------------- finalize: MLP per batch + (block 0) reg_loss ----------------
__global__ __launch_bounds__(128) void k_final(
    const float* __restrict__ y1pre, const float* __restrict__ b1,
    const float* __restrict__ W2, const float* __restrict__ b2,
    const float* __restrict__ W3, const float* __restrict__ b3,
    const float* __restrict__ W1, const float* __restrict__ Flast,
    const float* __restrict__ normsq, float* __restrict__ out)
{
  const int b = blockIdx.x, p = threadIdx.x;
  __shared__ float y1[PFD];
  __shared__ float red[PFD];
  const float extra = W1[(size_t)p * FUSED + (FUSED - 1)] * Flast[b];
  y1[p] = fmaxf(y1pre[(size_t)b * PFD + p] + extra + b1[p], 0.f);
  __syncthreads();
  float s = b2[p];
  for (int k = 0; k < PFD; ++k) s += y1[k] * W2[p * PFD + k];
  const float y2 = fmaxf(s, 0.f);
  red[p] = y2 * W3[p];
  __syncthreads();
  for (int off = 64; off > 0; off >>= 1) {
    if (p < off) red[p] += red[p + off];
    __syncthreads();
  }
  if (p == 0) {
    const float x = red[0] + b3[0];
    out[b] = 6.f / (1.f + expf(-x)) - 3.f;
  }
  if (b == 0) {   // fused k_reg: tmp = sqrt(64*64*128/128) = 64 exactly
    __syncthreads();
    red[p] = sqrtf(normsq[p]);
    __syncthreads();
    for (int off = 64; off > 0; off >>= 1) {
      if (p < off) red[p] += red[p + off];
      __syncthreads();
    }
    if (p == 0) out[BB] = 64.f * red[0] / (float)BB;
  }
}

extern "C" void kernel_launch(void* const* d_in, const int* in_sizes, int n_in,
                              void* d_out, int out_size, void* d_ws, size_t ws_size,
                              hipStream_t stream) {
  const float* audio  = (const float*)d_in[0];
  const float* vision = (const float*)d_in[1];
  const float* text   = (const float*)d_in[2];
  const float* W1     = (const float*)d_in[3];
  const float* b1     = (const float*)d_in[4];
  const float* W2     = (const float*)d_in[5];
  const float* b2     = (const float*)d_in[6];
  const float* W3     = (const float*)d_in[7];
  const float* b3     = (const float*)d_in[8];
  float* out = (float*)d_out;

  // ws layout (proven bound ws >= 279,183,872 B):
  // [y1pre 64KB][normsq][Flast] | Fh @131072 (147,193,856 B) |
  // parts @147,324,928 (1123*64KB = 73,596,928 B) -> total 220,921,856 B
  float* y1pre  = (float*)d_ws;
  float* normsq = y1pre + BB * PFD;
  float* Flast  = normsq + BB;
  _Float16* Fh  = (_Float16*)((char*)d_ws + 131072);
  float* parts  = (float*)((char*)d_ws + 147324928);

  k_initf<<<BB, 256, 0, stream>>>(Fh, y1pre, normsq, Flast);

  k_core<<<dim3(BB, 8, 2), 256, 0, stream>>>(audio, vision, text, Fh, normsq);
  k_planes<<<dim3(BB, 3), 256, 0, stream>>>(audio, vision, text, Fh, Flast, normsq);

  k_gemm<<<NBLK, 256, 0, stream>>>(W1, Fh, parts);
  k_red<<<dim3(64, 16), 256, 0, stream>>>(parts, y1pre);

  k_final<<<BB, PFD, 0, stream>>>(y1pre, b1, W2, b2, W3, b3, W1, Flast, normsq, out);
}